// Round 11
// baseline (160.348 us; speedup 1.0000x reference)
//
#include <hip/hip_runtime.h>
#include <hip/hip_bf16.h>
#include <stdint.h>

typedef __attribute__((ext_vector_type(8))) short  short8;   // 8 bf16 (4 VGPR) MFMA A/B frag
typedef __attribute__((ext_vector_type(4))) short  short4v;
typedef __attribute__((ext_vector_type(4))) float  float4v;  // 16x16 MFMA C/D frag
typedef __attribute__((ext_vector_type(16))) float f32x16;   // 32x32 MFMA C/D frag
typedef __attribute__((ext_vector_type(2))) unsigned int uint2v;

#define MFMA16(a, b, c) __builtin_amdgcn_mfma_f32_16x16x32_bf16((a), (b), (c), 0, 0, 0)
#define MFMA32(a, b, c) __builtin_amdgcn_mfma_f32_32x32x16_bf16((a), (b), (c), 0, 0, 0)

#define S_LEN  4096
#define NBATCH 4
#define EMB    1024
#define DD     64
#define NROWS  (NBATCH * S_LEN)  // 16384
#define SCL2   0.1803368801111204f  // (1/sqrt(64)) * log2(e), folded into Wq at wcvt

#define AS1 const __attribute__((address_space(1))) unsigned int*
#define AS3 __attribute__((address_space(3))) unsigned int*

static __device__ __forceinline__ short f2bf(float f) {
  uint32_t u = __float_as_uint(f);
  return (short)((u + 0x7FFFu + ((u >> 16) & 1u)) >> 16);
}
static __device__ __forceinline__ unsigned pk2(float a, float b) {
  union { __hip_bfloat162 h; unsigned u; } z;
  z.h = __float22bfloat162_rn(make_float2(a, b));
  return z.u;
}
static __device__ __forceinline__ short8 cvt8(float4v a, float4v b) {
  union { unsigned u[4]; short8 s; } z;
  z.u[0] = pk2(a[0], a[1]); z.u[1] = pk2(a[2], a[3]);
  z.u[2] = pk2(b[0], b[1]); z.u[3] = pk2(b[2], b[3]);
  return z.s;
}

// ============ Kernel 0: W fp32 -> bf16, reordered into 32-k panels ============
// Wb2 layout: [32 panels][192 rows][32 k] bf16; rows 0-63=Wq (pre-scaled by
// SCL2 -> scores arrive in log2 domain), 64-127=Wk, 128-191=Wv.
__global__ void wcvt_kernel(const float* __restrict__ Wq, const float* __restrict__ Wk,
                            const float* __restrict__ Wv, short* __restrict__ Wb2) {
  const int t   = blockIdx.x * 256 + threadIdx.x;  // 0..24575, 8 elems each
  const int row = t >> 7;
  const int k   = (t & 127) * 8;
  const float* src = (row < 64) ? (Wq + (size_t)row * EMB)
                   : (row < 128) ? (Wk + (size_t)(row - 64) * EMB)
                                 : (Wv + (size_t)(row - 128) * EMB);
  const float sc = (row < 64) ? SCL2 : 1.0f;
  float4v a = *(const float4v*)(src + k);
  float4v b = *(const float4v*)(src + k + 4);
#pragma unroll
  for (int i = 0; i < 4; ++i) { a[i] *= sc; b[i] *= sc; }
  *(short8*)(Wb2 + (((k >> 5) * 192 + row) << 5) + (k & 31)) = cvt8(a, b);
}

// ======================= Kernel 1: QKV projection GEMM =======================
// Round 18: M-tile 32 -> 64. Budget audit (R0-R10 reconciled): timed region =
// 2 harness 268-MB fills (82.6 us, fixed) + attn (~39) + qkv (~28-30) + wcvt
// (~2). qkv was at 3x its roofline: every 32-row block re-streamed ALL 384 KB
// of W panels (512 blocks x 384 KB = 196 MB) with 8 DMA instr/thread/step.
// Fix: block = TWO 32-row groups (waves 0-3 / 4-7), each running the exact
// proven engine, SHARING one Bs staging. W traffic halves (196 -> 98 MB),
// DMA instrs/step/CU 4096 -> 2560, staged bytes/CU 1 MB -> 640 KB, compute
// per staged byte doubles. LDS 80 KB (As 2x2x8 KB + Bs 2x24 KB); grid 256 =
// exactly 1 block/CU, no tail. Per-group addressing/fragments/writes are
// byte-identical to the old engine with m0 -> m0 + 32*g.
__global__ __launch_bounds__(512, 2) void qkv_kernel(
    const float* __restrict__ x, const short* __restrict__ Wb2,
    short* __restrict__ Qb, short* __restrict__ Kb, short* __restrict__ Vt) {
  __shared__ float As[2][2][2048];  // [buf][group] 8 KB  (32 rows x 64 k fp32)
  __shared__ short Bs[2][12288];    // [buf] 24 KB (2 panels x 192 x 32 bf16)

  const int tid  = threadIdx.x;
  const int w    = tid >> 6;        // 0..7
  const int lane = tid & 63;
  const int ln   = lane & 15;
  const int quad = lane >> 4;
  const int g    = w >> 2;          // group 0/1 -> rows m0+32g..+31
  const int w4   = w & 3;           // wave within group
  const int m0   = blockIdx.x * 64;
  const int m0g  = m0 + 32 * g;
  const int wr   = w4 & 1;
  const int wc   = w4 >> 1;

  const int tA0 = 2 * w4, tA1 = 2 * w4 + 1;
  const float* xA0 = x + (size_t)(m0g + ((tA0 >> 2) << 4) + (lane >> 2)) * EMB
                       + ((tA0 & 3) * 4 + (lane & 3)) * 4;
  const float* xA1 = x + (size_t)(m0g + ((tA1 >> 2) << 4) + (lane >> 2)) * EMB
                       + ((tA1 & 3) * 4 + (lane & 3)) * 4;
  const short* wB = Wb2 + (size_t)(3 * w) * 512 + lane * 8;   // 8 waves x 3 seg

#define STAGE(S, BUF) do {                                                      \
    __builtin_amdgcn_global_load_lds((AS1)(xA0 + (S) * 64),                     \
        (AS3)&As[BUF][g][tA0 * 256], 16, 0, 0);                                 \
    __builtin_amdgcn_global_load_lds((AS1)(xA1 + (S) * 64),                     \
        (AS3)&As[BUF][g][tA1 * 256], 16, 0, 0);                                 \
    _Pragma("unroll")                                                           \
    for (int j = 0; j < 3; ++j)                                                 \
      __builtin_amdgcn_global_load_lds((AS1)(wB + (size_t)(S) * 12288 + j * 512),\
          (AS3)&Bs[BUF][(3 * w + j) * 512], 16, 0, 0);                          \
  } while (0)

  const float4v zz = {0.f, 0.f, 0.f, 0.f};
  float4v acc[6] = {zz, zz, zz, zz, zz, zz};

  STAGE(0, 0);
  int buf = 0;
  for (int s = 0; s < 16; ++s) {
    __syncthreads();                       // drains this buf's DMA (vmcnt 0)
    if (s + 1 < 16) STAGE(s + 1, buf ^ 1); // overlaps with compute below
    short8 aF[2];
#pragma unroll
    for (int h = 0; h < 2; ++h) {
      const int ai = (wr * 4 + 2 * h + (quad >> 1)) * 256 + (ln * 4 + (quad & 1) * 2) * 4;
      const float4v lo = *(const float4v*)&As[buf][g][ai];
      const float4v hi = *(const float4v*)&As[buf][g][ai + 4];
      aF[h] = cvt8(lo, hi);
    }
#pragma unroll
    for (int f = 0; f < 6; ++f) {
      const int cf = wc * 6 + f;
      const short8 b0 = *(const short8*)&Bs[buf][(cf * 16 + ln) * 32 + quad * 8];
      const short8 b1 = *(const short8*)&Bs[buf][6144 + (cf * 16 + ln) * 32 + quad * 8];
      if (wc == 0 || f < 2) {
        acc[f] = MFMA16(aF[0], b0, acc[f]);
        acc[f] = MFMA16(aF[1], b1, acc[f]);
      } else {  // V frags: operand swap -> transposed output
        acc[f] = MFMA16(b0, aF[0], acc[f]);
        acc[f] = MFMA16(b1, aF[1], acc[f]);
      }
    }
    buf ^= 1;
  }
#undef STAGE

  const int b  = m0g >> 12;
  const int sb = m0g & (S_LEN - 1);
  if (wc == 0) {
#pragma unroll
    for (int f = 0; f < 6; ++f)
#pragma unroll
      for (int r = 0; r < 4; ++r) {
        const int row = m0g + wr * 16 + quad * 4 + r;
        if (f < 4) Qb[(size_t)row * DD + f * 16 + ln] = f2bf(acc[f][r]);
        else       Kb[(size_t)row * DD + (f - 4) * 16 + ln] = f2bf(acc[f][r]);
      }
  } else {
#pragma unroll
    for (int f = 0; f < 2; ++f)
#pragma unroll
      for (int r = 0; r < 4; ++r) {
        const int row = m0g + wr * 16 + quad * 4 + r;
        Kb[(size_t)row * DD + 32 + f * 16 + ln] = f2bf(acc[f][r]);
      }
#pragma unroll
    for (int f = 2; f < 6; ++f)
#pragma unroll
      for (int r = 0; r < 4; ++r) {
        const int d = (f - 2) * 16 + quad * 4 + r;
        Vt[((size_t)b * DD + d) * S_LEN + sb + wr * 16 + ln] = f2bf(acc[f][r]);
      }
  }
}

// ======================= Kernel 2: causal flash attention =======================
// Round 17 engine, UNCHANGED (R10): K/V reuse over band pairs; in-register
// swapped-QK^T 32x32 softmax (R7-verified permlane mapping). Attn has pinned
// at ~39-44 us across latency/occupancy/critical-path/traffic interventions;
// this round targets qkv instead.
__global__ __launch_bounds__(512, 2) void attn_kernel(
    const short* __restrict__ Qb, const short* __restrict__ Kb,
    const short* __restrict__ Vt, float* __restrict__ out) {
  __shared__ float sbuf[8][2048];   // 64 KB: one band-pass of 8-wave partials
  __shared__ float llds[8][32];

  const int tid  = threadIdx.x;
  const int w    = tid >> 6;
  const int lane = tid & 63;
  const int l31  = lane & 31;
  const int hi   = lane >> 5;
  const int g    = blockIdx.x;
  const int b    = g & 3;
  const int k2   = g >> 2;          // pair index 0..63
  const short* Kbase = Kb + (size_t)b * S_LEN * DD;
  const short* Vbase = Vt + (size_t)b * DD * S_LEN;

  const int bandA = 2 * k2, bandB = 2 * k2 + 1;
  const int qbA   = bandA * 32;
  const int qgA   = b * S_LEN + qbA;          // band A global row base
  const int qglobA = qbA + l31;
  const int qglobB = qbA + 32 + l31;

  // Q for both bands: lane holds Q[row l31][dk*16 + hi*8 + 0..7]
  short8 qA[4], qB[4];
#pragma unroll
  for (int dk = 0; dk < 4; ++dk) {
    qA[dk] = *(const short8*)(Qb + (size_t)(qgA + l31) * DD + dk * 16 + hi * 8);
    qB[dk] = *(const short8*)(Qb + (size_t)(qgA + 32 + l31) * DD + dk * 16 + hi * 8);
  }

  f32x16 oA0, oA1, oB0, oB1, zz16;
#pragma unroll
  for (int e = 0; e < 16; ++e) { oA0[e] = oA1[e] = oB0[e] = oB1[e] = 0.f; zz16[e] = 0.f; }
  float lpA = 0.f, lpB = 0.f;

  const int itN = bandB + 1;   // tiles 0..bandB

  for (int it = w; it < itN; it += 8) {
    const int kv0 = it * 32;
    short8 kf[4];
#pragma unroll
    for (int dk = 0; dk < 4; ++dk)
      kf[dk] = *(const short8*)(Kbase + (size_t)(kv0 + l31) * DD + dk * 16 + hi * 8);
    short8 vf[2][2];
#pragma unroll
    for (int df = 0; df < 2; ++df)
#pragma unroll
      for (int kc = 0; kc < 2; ++kc)
        vf[df][kc] = *(const short8*)(Vbase + (size_t)(df * 32 + l31) * S_LEN + kv0 + kc * 16 + hi * 8);

    // ---- shared per-band engine: QK chain, exp2(+mask), pack, PV ----
#define BAND_STEP(QV, OV0, OV1, LP, QGLOB, DIAG, SKIP) do {                    \
    if (!(SKIP)) {                                                             \
      f32x16 s = MFMA32(kf[0], (QV)[0], zz16);                                 \
      _Pragma("unroll")                                                        \
      for (int dk = 1; dk < 4; ++dk) s = MFMA32(kf[dk], (QV)[dk], s);          \
      if (DIAG) {                                                              \
        _Pragma("unroll")                                                      \
        for (int e = 0; e < 16; ++e) {                                         \
          const int kvl = (e & 3) + 8 * (e >> 2) + 4 * hi;                     \
          float e0 = __builtin_amdgcn_exp2f(fminf(s[e], 60.0f));               \
          if (kv0 + kvl > (QGLOB)) e0 = 0.f;                                   \
          s[e] = e0; (LP) += e0;                                               \
        }                                                                      \
      } else {                                                                 \
        _Pragma("unroll")                                                      \
        for (int e = 0; e < 16; ++e) {                                         \
          float e0 = __builtin_amdgcn_exp2f(fminf(s[e], 60.0f));               \
          s[e] = e0; (LP) += e0;                                               \
        }                                                                      \
      }                                                                        \
      unsigned ua, ub, uc, ud, ue, uf2, ug, uh;                                \
      asm("v_cvt_pk_bf16_f32 %0, %1, %2" : "=v"(ua) : "v"(s[0]),  "v"(s[1]));  \
      asm("v_cvt_pk_bf16_f32 %0, %1, %2" : "=v"(ub) : "v"(s[2]),  "v"(s[3]));  \
      asm("v_cvt_pk_bf16_f32 %0, %1, %2" : "=v"(uc) : "v"(s[4]),  "v"(s[5]));  \
      asm("v_cvt_pk_bf16_f32 %0, %1, %2" : "=v"(ud) : "v"(s[6]),  "v"(s[7]));  \
      asm("v_cvt_pk_bf16_f32 %0, %1, %2" : "=v"(ue) : "v"(s[8]),  "v"(s[9]));  \
      asm("v_cvt_pk_bf16_f32 %0, %1, %2" : "=v"(uf2): "v"(s[10]), "v"(s[11])); \
      asm("v_cvt_pk_bf16_f32 %0, %1, %2" : "=v"(ug) : "v"(s[12]), "v"(s[13])); \
      asm("v_cvt_pk_bf16_f32 %0, %1, %2" : "=v"(uh) : "v"(s[14]), "v"(s[15])); \
      uint2v r0 = __builtin_amdgcn_permlane32_swap(ua, uc, false, false);      \
      uint2v r1 = __builtin_amdgcn_permlane32_swap(ub, ud, false, false);      \
      uint2v r2 = __builtin_amdgcn_permlane32_swap(ue, ug, false, false);      \
      uint2v r3 = __builtin_amdgcn_permlane32_swap(uf2, uh, false, false);     \
      union { unsigned uu[4]; short8 s8; } p0, p1;                             \
      p0.uu[0] = r0[0]; p0.uu[1] = r1[0]; p0.uu[2] = r0[1]; p0.uu[3] = r1[1];  \
      p1.uu[0] = r2[0]; p1.uu[1] = r3[0]; p1.uu[2] = r2[1]; p1.uu[3] = r3[1];  \
      (OV0) = MFMA32(p0.s8, vf[0][0], (OV0));                                  \
      (OV0) = MFMA32(p1.s8, vf[0][1], (OV0));                                  \
      (OV1) = MFMA32(p0.s8, vf[1][0], (OV1));                                  \
      (OV1) = MFMA32(p1.s8, vf[1][1], (OV1));                                  \
    }                                                                          \
  } while (0)

    BAND_STEP(qA, oA0, oA1, lpA, qglobA, it == bandA, it > bandA);
    BAND_STEP(qB, oB0, oB1, lpB, qglobB, it == bandB, false);
#undef BAND_STEP
  }

  // ---- epilogue: two 32-q passes (band A then band B), reusing sbuf ----
#define EPILOG(OV0, OV1, LP, ROW0) do {                                        \
    float lpt = (LP) + __shfl_xor((LP), 32);                                   \
    float* pw = &sbuf[w][0];                                                   \
    _Pragma("unroll")                                                          \
    for (int e = 0; e < 16; ++e) {                                             \
      const int ql = (e & 3) + 8 * (e >> 2) + 4 * hi;                          \
      pw[ql * 64 + l31]      = (OV0)[e];                                       \
      pw[ql * 64 + 32 + l31] = (OV1)[e];                                       \
    }                                                                          \
    if (hi == 0) llds[w][l31] = lpt;                                           \
    __syncthreads();                                                           \
    _Pragma("unroll")                                                          \
    for (int jx = 0; jx < 4; ++jx) {                                           \
      const int idx = tid + jx * 512;                                          \
      const int row = idx >> 6, col = idx & 63;                                \
      float sum = 0.f, lt = 0.f;                                               \
      _Pragma("unroll")                                                        \
      for (int wi = 0; wi < 8; ++wi) {                                         \
        sum += sbuf[wi][row * 64 + col];                                       \
        lt  += llds[wi][row];                                                  \
      }                                                                        \
      out[(size_t)((ROW0) + row) * DD + col] = sum * __builtin_amdgcn_rcpf(lt);\
    }                                                                          \
    __syncthreads();                                                           \
  } while (0)

  EPILOG(oA0, oA1, lpA, qgA);
  EPILOG(oB0, oB1, lpB, qgA + 32);
#undef EPILOG
}

extern "C" void kernel_launch(void* const* d_in, const int* in_sizes, int n_in,
                              void* d_out, int out_size, void* d_ws, size_t ws_size,
                              hipStream_t stream) {
  const float* x  = (const float*)d_in[0];
  const float* Wq = (const float*)d_in[1];
  const float* Wk = (const float*)d_in[2];
  const float* Wv = (const float*)d_in[3];

  short* Qb  = (short*)d_ws;                       // 2 MB
  short* Kb  = Qb + (size_t)NROWS * DD;            // 2 MB
  short* Vt  = Kb + (size_t)NROWS * DD;            // 2 MB  [b][d][s]
  short* Wb2 = Vt + (size_t)NROWS * DD;            // 384 KB panels

  wcvt_kernel<<<dim3(96), dim3(256), 0, stream>>>(Wq, Wk, Wv, Wb2);
  qkv_kernel<<<dim3(NROWS / 64), dim3(512), 0, stream>>>(x, Wb2, Qb, Kb, Vt);
  attn_kernel<<<dim3(NBATCH * 64), dim3(512), 0, stream>>>(Qb, Kb, Vt, (float*)d_out);
}

// Round 12
// 148.209 us; speedup vs baseline: 1.0819x; 1.0819x over previous
//
#include <hip/hip_runtime.h>
#include <hip/hip_bf16.h>
#include <stdint.h>

typedef __attribute__((ext_vector_type(8))) short  short8;   // 8 bf16 (4 VGPR) MFMA A/B frag
typedef __attribute__((ext_vector_type(4))) short  short4v;
typedef __attribute__((ext_vector_type(4))) float  float4v;  // 16x16 MFMA C/D frag
typedef __attribute__((ext_vector_type(16))) float f32x16;   // 32x32 MFMA C/D frag
typedef __attribute__((ext_vector_type(2))) unsigned int uint2v;

#define MFMA16(a, b, c) __builtin_amdgcn_mfma_f32_16x16x32_bf16((a), (b), (c), 0, 0, 0)
#define MFMA32(a, b, c) __builtin_amdgcn_mfma_f32_32x32x16_bf16((a), (b), (c), 0, 0, 0)

#define S_LEN  4096
#define NBATCH 4
#define EMB    1024
#define DD     64
#define NROWS  (NBATCH * S_LEN)  // 16384
#define SCL2   0.1803368801111204f  // (1/sqrt(64)) * log2(e), folded into Wq at wcvt

#define AS1 const __attribute__((address_space(1))) unsigned int*
#define AS3 __attribute__((address_space(3))) unsigned int*

static __device__ __forceinline__ short f2bf(float f) {
  uint32_t u = __float_as_uint(f);
  return (short)((u + 0x7FFFu + ((u >> 16) & 1u)) >> 16);
}
static __device__ __forceinline__ unsigned pk2(float a, float b) {
  union { __hip_bfloat162 h; unsigned u; } z;
  z.h = __float22bfloat162_rn(make_float2(a, b));
  return z.u;
}
static __device__ __forceinline__ short8 cvt8(float4v a, float4v b) {
  union { unsigned u[4]; short8 s; } z;
  z.u[0] = pk2(a[0], a[1]); z.u[1] = pk2(a[2], a[3]);
  z.u[2] = pk2(b[0], b[1]); z.u[3] = pk2(b[2], b[3]);
  return z.s;
}

// ============ Kernel 0: W fp32 -> bf16, reordered into 32-k panels ============
// Wb2 layout: [32 panels][192 rows][32 k] bf16; rows 0-63=Wq (pre-scaled by
// SCL2 -> scores arrive in log2 domain), 64-127=Wk, 128-191=Wv.
__global__ void wcvt_kernel(const float* __restrict__ Wq, const float* __restrict__ Wk,
                            const float* __restrict__ Wv, short* __restrict__ Wb2) {
  const int t   = blockIdx.x * 256 + threadIdx.x;  // 0..24575, 8 elems each
  const int row = t >> 7;
  const int k   = (t & 127) * 8;
  const float* src = (row < 64) ? (Wq + (size_t)row * EMB)
                   : (row < 128) ? (Wk + (size_t)(row - 64) * EMB)
                                 : (Wv + (size_t)(row - 128) * EMB);
  const float sc = (row < 64) ? SCL2 : 1.0f;
  float4v a = *(const float4v*)(src + k);
  float4v b = *(const float4v*)(src + k + 4);
#pragma unroll
  for (int i = 0; i < 4; ++i) { a[i] *= sc; b[i] *= sc; }
  *(short8*)(Wb2 + (((k >> 5) * 192 + row) << 5) + (k & 31)) = cvt8(a, b);
}

// ======================= Kernel 1: QKV projection GEMM =======================
// Round 19: back to the proven M32 shape (R11's M64 single-block regressed:
// one 512-thr barrier chain, no co-resident block to hide the DMA drain) +
// the lever R11's counters exposed: SQ_LDS_BANK_CONFLICT = 8.9M cycles
// (~35K/CU ~= 14 us/CU) on the As fragment reads. Root cause: read addr =
// R*1024 + ln*64 + (quad&1)*32 -> addr mod 128 takes only 4 values (row
// stride 64B aliases rows mod 2) -> 16 lanes per 16B position per b128.
// Fix (T2/m173 both-sides swizzle; global_load_lds writes linearly so the
// GLOBAL source is pre-swizzled): within each 1KB slot (16 rows x 4 chunks),
// row r's k-chunk kb lives at position kb ^ ((r>>1)&3).
//   write: lane l fetches k-block (l&3) ^ ((l>>3)&3)  (same 64B row-group ->
//          coalescing unchanged, data bit-identical)
//   read:  lo at chunk (2(quad&1)) ^ ((ln>>1)&3), hi at +1^same
// -> addr bits 4-6 now carry {kb' (2b), ln&1}: all 8 residues mod 128
// uniformly covered, 8 lanes each = conflict-free b128.
__global__ __launch_bounds__(256, 2) void qkv_kernel(
    const float* __restrict__ x, const short* __restrict__ Wb2,
    short* __restrict__ Qb, short* __restrict__ Kb, short* __restrict__ Vt) {
  __shared__ float As[2][2048];   // 2 x 8 KB  (32 rows x 64 k fp32, slot order)
  __shared__ short Bs[2][12288];  // 2 x 24 KB (2 panels x 192 x 32 bf16, identity)

  const int tid  = threadIdx.x;
  const int w    = tid >> 6;
  const int lane = tid & 63;
  const int ln   = lane & 15;
  const int quad = lane >> 4;
  const int m0   = blockIdx.x * 32;
  const int wr   = w & 1;
  const int wc   = w >> 1;

  const int tA0 = 2 * w, tA1 = 2 * w + 1;
  // k-block swizzled by row bits (lane>>3)&3 -- see header comment.
  const int kbs = (lane & 3) ^ ((lane >> 3) & 3);
  const float* xA0 = x + (size_t)(m0 + ((tA0 >> 2) << 4) + (lane >> 2)) * EMB
                       + ((tA0 & 3) * 4 + kbs) * 4;
  const float* xA1 = x + (size_t)(m0 + ((tA1 >> 2) << 4) + (lane >> 2)) * EMB
                       + ((tA1 & 3) * 4 + kbs) * 4;
  const short* wB = Wb2 + (size_t)(6 * w) * 512 + lane * 8;

#define STAGE(S, BUF) do {                                                      \
    __builtin_amdgcn_global_load_lds((AS1)(xA0 + (S) * 64),                     \
        (AS3)&As[BUF][tA0 * 256], 16, 0, 0);                                    \
    __builtin_amdgcn_global_load_lds((AS1)(xA1 + (S) * 64),                     \
        (AS3)&As[BUF][tA1 * 256], 16, 0, 0);                                    \
    _Pragma("unroll")                                                           \
    for (int j = 0; j < 6; ++j)                                                 \
      __builtin_amdgcn_global_load_lds((AS1)(wB + (size_t)(S) * 12288 + j * 512),\
          (AS3)&Bs[BUF][(6 * w + j) * 512], 16, 0, 0);                          \
  } while (0)

  const float4v zz = {0.f, 0.f, 0.f, 0.f};
  float4v acc[6] = {zz, zz, zz, zz, zz, zz};

  const int sw = (ln >> 1) & 3;   // read-side swizzle term

  STAGE(0, 0);
  int buf = 0;
  for (int s = 0; s < 16; ++s) {
    __syncthreads();                       // drains this buf's DMA (vmcnt 0)
    if (s + 1 < 16) STAGE(s + 1, buf ^ 1); // overlaps with compute below
    short8 aF[2];
#pragma unroll
    for (int h = 0; h < 2; ++h) {
      const int rb = (wr * 4 + 2 * h + (quad >> 1)) * 256 + ln * 16;
      const float4v lo = *(const float4v*)&As[buf][rb + ((((quad & 1) * 2)    ) ^ sw) * 4];
      const float4v hi = *(const float4v*)&As[buf][rb + ((((quad & 1) * 2) + 1) ^ sw) * 4];
      aF[h] = cvt8(lo, hi);
    }
#pragma unroll
    for (int f = 0; f < 6; ++f) {
      const int cf = wc * 6 + f;
      const short8 b0 = *(const short8*)&Bs[buf][(cf * 16 + ln) * 32 + quad * 8];
      const short8 b1 = *(const short8*)&Bs[buf][6144 + (cf * 16 + ln) * 32 + quad * 8];
      if (wc == 0 || f < 2) {
        acc[f] = MFMA16(aF[0], b0, acc[f]);
        acc[f] = MFMA16(aF[1], b1, acc[f]);
      } else {  // V frags: operand swap -> transposed output
        acc[f] = MFMA16(b0, aF[0], acc[f]);
        acc[f] = MFMA16(b1, aF[1], acc[f]);
      }
    }
    buf ^= 1;
  }
#undef STAGE

  const int b  = m0 >> 12;
  const int sb = m0 & (S_LEN - 1);
  if (wc == 0) {
#pragma unroll
    for (int f = 0; f < 6; ++f)
#pragma unroll
      for (int r = 0; r < 4; ++r) {
        const int row = m0 + wr * 16 + quad * 4 + r;
        if (f < 4) Qb[(size_t)row * DD + f * 16 + ln] = f2bf(acc[f][r]);
        else       Kb[(size_t)row * DD + (f - 4) * 16 + ln] = f2bf(acc[f][r]);
      }
  } else {
#pragma unroll
    for (int f = 0; f < 2; ++f)
#pragma unroll
      for (int r = 0; r < 4; ++r) {
        const int row = m0 + wr * 16 + quad * 4 + r;
        Kb[(size_t)row * DD + 32 + f * 16 + ln] = f2bf(acc[f][r]);
      }
#pragma unroll
    for (int f = 2; f < 6; ++f)
#pragma unroll
      for (int r = 0; r < 4; ++r) {
        const int d = (f - 2) * 16 + quad * 4 + r;
        Vt[((size_t)b * DD + d) * S_LEN + sb + wr * 16 + ln] = f2bf(acc[f][r]);
      }
  }
}

// ======================= Kernel 2: causal flash attention =======================
// Round 17 engine, UNCHANGED (R10): K/V reuse over band pairs; in-register
// swapped-QK^T 32x32 softmax (R7-verified permlane mapping). Loop has zero
// LDS ops; epilogue conflicts measured ~0 (R9).
__global__ __launch_bounds__(512, 2) void attn_kernel(
    const short* __restrict__ Qb, const short* __restrict__ Kb,
    const short* __restrict__ Vt, float* __restrict__ out) {
  __shared__ float sbuf[8][2048];   // 64 KB: one band-pass of 8-wave partials
  __shared__ float llds[8][32];

  const int tid  = threadIdx.x;
  const int w    = tid >> 6;
  const int lane = tid & 63;
  const int l31  = lane & 31;
  const int hi   = lane >> 5;
  const int g    = blockIdx.x;
  const int b    = g & 3;
  const int k2   = g >> 2;          // pair index 0..63
  const short* Kbase = Kb + (size_t)b * S_LEN * DD;
  const short* Vbase = Vt + (size_t)b * DD * S_LEN;

  const int bandA = 2 * k2, bandB = 2 * k2 + 1;
  const int qbA   = bandA * 32;
  const int qgA   = b * S_LEN + qbA;          // band A global row base
  const int qglobA = qbA + l31;
  const int qglobB = qbA + 32 + l31;

  // Q for both bands: lane holds Q[row l31][dk*16 + hi*8 + 0..7]
  short8 qA[4], qB[4];
#pragma unroll
  for (int dk = 0; dk < 4; ++dk) {
    qA[dk] = *(const short8*)(Qb + (size_t)(qgA + l31) * DD + dk * 16 + hi * 8);
    qB[dk] = *(const short8*)(Qb + (size_t)(qgA + 32 + l31) * DD + dk * 16 + hi * 8);
  }

  f32x16 oA0, oA1, oB0, oB1, zz16;
#pragma unroll
  for (int e = 0; e < 16; ++e) { oA0[e] = oA1[e] = oB0[e] = oB1[e] = 0.f; zz16[e] = 0.f; }
  float lpA = 0.f, lpB = 0.f;

  const int itN = bandB + 1;   // tiles 0..bandB

  for (int it = w; it < itN; it += 8) {
    const int kv0 = it * 32;
    short8 kf[4];
#pragma unroll
    for (int dk = 0; dk < 4; ++dk)
      kf[dk] = *(const short8*)(Kbase + (size_t)(kv0 + l31) * DD + dk * 16 + hi * 8);
    short8 vf[2][2];
#pragma unroll
    for (int df = 0; df < 2; ++df)
#pragma unroll
      for (int kc = 0; kc < 2; ++kc)
        vf[df][kc] = *(const short8*)(Vbase + (size_t)(df * 32 + l31) * S_LEN + kv0 + kc * 16 + hi * 8);

    // ---- shared per-band engine: QK chain, exp2(+mask), pack, PV ----
#define BAND_STEP(QV, OV0, OV1, LP, QGLOB, DIAG, SKIP) do {                    \
    if (!(SKIP)) {                                                             \
      f32x16 s = MFMA32(kf[0], (QV)[0], zz16);                                 \
      _Pragma("unroll")                                                        \
      for (int dk = 1; dk < 4; ++dk) s = MFMA32(kf[dk], (QV)[dk], s);          \
      if (DIAG) {                                                              \
        _Pragma("unroll")                                                      \
        for (int e = 0; e < 16; ++e) {                                         \
          const int kvl = (e & 3) + 8 * (e >> 2) + 4 * hi;                     \
          float e0 = __builtin_amdgcn_exp2f(fminf(s[e], 60.0f));               \
          if (kv0 + kvl > (QGLOB)) e0 = 0.f;                                   \
          s[e] = e0; (LP) += e0;                                               \
        }                                                                      \
      } else {                                                                 \
        _Pragma("unroll")                                                      \
        for (int e = 0; e < 16; ++e) {                                         \
          float e0 = __builtin_amdgcn_exp2f(fminf(s[e], 60.0f));               \
          s[e] = e0; (LP) += e0;                                               \
        }                                                                      \
      }                                                                        \
      unsigned ua, ub, uc, ud, ue, uf2, ug, uh;                                \
      asm("v_cvt_pk_bf16_f32 %0, %1, %2" : "=v"(ua) : "v"(s[0]),  "v"(s[1]));  \
      asm("v_cvt_pk_bf16_f32 %0, %1, %2" : "=v"(ub) : "v"(s[2]),  "v"(s[3]));  \
      asm("v_cvt_pk_bf16_f32 %0, %1, %2" : "=v"(uc) : "v"(s[4]),  "v"(s[5]));  \
      asm("v_cvt_pk_bf16_f32 %0, %1, %2" : "=v"(ud) : "v"(s[6]),  "v"(s[7]));  \
      asm("v_cvt_pk_bf16_f32 %0, %1, %2" : "=v"(ue) : "v"(s[8]),  "v"(s[9]));  \
      asm("v_cvt_pk_bf16_f32 %0, %1, %2" : "=v"(uf2): "v"(s[10]), "v"(s[11])); \
      asm("v_cvt_pk_bf16_f32 %0, %1, %2" : "=v"(ug) : "v"(s[12]), "v"(s[13])); \
      asm("v_cvt_pk_bf16_f32 %0, %1, %2" : "=v"(uh) : "v"(s[14]), "v"(s[15])); \
      uint2v r0 = __builtin_amdgcn_permlane32_swap(ua, uc, false, false);      \
      uint2v r1 = __builtin_amdgcn_permlane32_swap(ub, ud, false, false);      \
      uint2v r2 = __builtin_amdgcn_permlane32_swap(ue, ug, false, false);      \
      uint2v r3 = __builtin_amdgcn_permlane32_swap(uf2, uh, false, false);     \
      union { unsigned uu[4]; short8 s8; } p0, p1;                             \
      p0.uu[0] = r0[0]; p0.uu[1] = r1[0]; p0.uu[2] = r0[1]; p0.uu[3] = r1[1];  \
      p1.uu[0] = r2[0]; p1.uu[1] = r3[0]; p1.uu[2] = r2[1]; p1.uu[3] = r3[1];  \
      (OV0) = MFMA32(p0.s8, vf[0][0], (OV0));                                  \
      (OV0) = MFMA32(p1.s8, vf[0][1], (OV0));                                  \
      (OV1) = MFMA32(p0.s8, vf[1][0], (OV1));                                  \
      (OV1) = MFMA32(p1.s8, vf[1][1], (OV1));                                  \
    }                                                                          \
  } while (0)

    BAND_STEP(qA, oA0, oA1, lpA, qglobA, it == bandA, it > bandA);
    BAND_STEP(qB, oB0, oB1, lpB, qglobB, it == bandB, false);
#undef BAND_STEP
  }

  // ---- epilogue: two 32-q passes (band A then band B), reusing sbuf ----
#define EPILOG(OV0, OV1, LP, ROW0) do {                                        \
    float lpt = (LP) + __shfl_xor((LP), 32);                                   \
    float* pw = &sbuf[w][0];                                                   \
    _Pragma("unroll")                                                          \
    for (int e = 0; e < 16; ++e) {                                             \
      const int ql = (e & 3) + 8 * (e >> 2) + 4 * hi;                          \
      pw[ql * 64 + l31]      = (OV0)[e];                                       \
      pw[ql * 64 + 32 + l31] = (OV1)[e];                                       \
    }                                                                          \
    if (hi == 0) llds[w][l31] = lpt;                                           \
    __syncthreads();                                                           \
    _Pragma("unroll")                                                          \
    for (int jx = 0; jx < 4; ++jx) {                                           \
      const int idx = tid + jx * 512;                                          \
      const int row = idx >> 6, col = idx & 63;                                \
      float sum = 0.f, lt = 0.f;                                               \
      _Pragma("unroll")                                                        \
      for (int wi = 0; wi < 8; ++wi) {                                         \
        sum += sbuf[wi][row * 64 + col];                                       \
        lt  += llds[wi][row];                                                  \
      }                                                                        \
      out[(size_t)((ROW0) + row) * DD + col] = sum * __builtin_amdgcn_rcpf(lt);\
    }                                                                          \
    __syncthreads();                                                           \
  } while (0)

  EPILOG(oA0, oA1, lpA, qgA);
  EPILOG(oB0, oB1, lpB, qgA + 32);
#undef EPILOG
}

extern "C" void kernel_launch(void* const* d_in, const int* in_sizes, int n_in,
                              void* d_out, int out_size, void* d_ws, size_t ws_size,
                              hipStream_t stream) {
  const float* x  = (const float*)d_in[0];
  const float* Wq = (const float*)d_in[1];
  const float* Wk = (const float*)d_in[2];
  const float* Wv = (const float*)d_in[3];

  short* Qb  = (short*)d_ws;                       // 2 MB
  short* Kb  = Qb + (size_t)NROWS * DD;            // 2 MB
  short* Vt  = Kb + (size_t)NROWS * DD;            // 2 MB  [b][d][s]
  short* Wb2 = Vt + (size_t)NROWS * DD;            // 384 KB panels

  wcvt_kernel<<<dim3(96), dim3(256), 0, stream>>>(Wq, Wk, Wv, Wb2);
  qkv_kernel<<<dim3(NROWS / 32), dim3(256), 0, stream>>>(x, Wb2, Qb, Kb, Vt);
  attn_kernel<<<dim3(NBATCH * 64), dim3(512), 0, stream>>>(Qb, Kb, Vt, (float*)d_out);
}